// Round 1
// baseline (321.341 us; speedup 1.0000x reference)
//
#include <hip/hip_runtime.h>
#include <math.h>

// Word2Vec negative-sampling loss.
// B=16384 blocks, 256 threads each. Block b computes losses[b].
// Each 32-lane half-wave gathers one 512B embedding row (float4/lane,
// fully coalesced), dots vs register-resident Z fragment, butterfly-reduces.

#define O_WIN 10
#define K_NEG 10
#define DIM   128
#define ROWS  (O_WIN * (K_NEG + 1))   // 110 score rows per batch element

__global__ __launch_bounds__(256) void w2v_neg_loss_kernel(
    const float* __restrict__ center,    // [VOCAB, 128]
    const float* __restrict__ outside,   // [VOCAB, 128]
    const int*   __restrict__ cidx,      // [B]
    const int*   __restrict__ owi,       // [B, O]
    const int*   __restrict__ negs,      // [B, O, K]
    float*       __restrict__ out)       // [B]
{
    const int b    = blockIdx.x;
    const int tid  = threadIdx.x;
    const int lane = tid & 31;   // lane within 32-lane gather group
    const int grp  = tid >> 5;   // 8 gather groups per block

    __shared__ int   s_ow[O_WIN];
    __shared__ int   s_neg[O_WIN * K_NEG];
    __shared__ float s_part[8];

    if (tid < O_WIN)         s_ow[tid]  = owi[(size_t)b * O_WIN + tid];
    if (tid < O_WIN * K_NEG) s_neg[tid] = negs[(size_t)b * O_WIN * K_NEG + tid];
    __syncthreads();

    // Z fragment: lane owns center[c][lane*4 .. lane*4+3], lives in VGPRs.
    const int c = cidx[b];
    const float4 zf = *reinterpret_cast<const float4*>(
        center + (size_t)c * DIM + lane * 4);

    float acc = 0.f;

    // 110 rows round-robined over the 8 groups.
    for (int r = grp; r < ROWS; r += 8) {
        const int o  = r / 11;
        const int j  = r - o * 11;        // 0 = positive, 1..10 = negatives
        const int ow = s_ow[o];
        if (ow == 0) continue;            // padded outside word: whole group masked

        int   idx;
        float sgn;
        if (j == 0) { idx = ow;                       sgn =  1.f; }
        else        { idx = s_neg[o * K_NEG + j - 1]; sgn = -1.f; }
        if (idx == 0) continue;           // masked negative sample

        const float4 w = *reinterpret_cast<const float4*>(
            outside + (size_t)idx * DIM + lane * 4);

        float p = w.x * zf.x + w.y * zf.y + w.z * zf.z + w.w * zf.w;
        // butterfly sum across the 32-lane group (masks <32 never cross halves)
        p += __shfl_xor(p, 1);
        p += __shfl_xor(p, 2);
        p += __shfl_xor(p, 4);
        p += __shfl_xor(p, 8);
        p += __shfl_xor(p, 16);

        const float score = sgn * p;
        // stable log-sigmoid: min(x,0) - log1p(exp(-|x|))
        const float ls = fminf(score, 0.f) - log1pf(expf(-fabsf(score)));
        if (lane == 0) acc += ls;
    }

    if (lane == 0) s_part[grp] = acc;
    __syncthreads();

    if (tid == 0) {
        float t = 0.f;
        #pragma unroll
        for (int i = 0; i < 8; ++i) t += s_part[i];
        out[b] = -t;
    }
}

extern "C" void kernel_launch(void* const* d_in, const int* in_sizes, int n_in,
                              void* d_out, int out_size, void* d_ws, size_t ws_size,
                              hipStream_t stream) {
    const float* center  = (const float*)d_in[0];
    const float* outside = (const float*)d_in[1];
    const int*   cw      = (const int*)d_in[2];
    const int*   ow      = (const int*)d_in[3];
    const int*   ng      = (const int*)d_in[4];
    float*       out     = (float*)d_out;

    const int B = in_sizes[2];   // 16384
    w2v_neg_loss_kernel<<<B, 256, 0, stream>>>(center, outside, cw, ow, ng, out);
}

// Round 3
// 222.133 us; speedup vs baseline: 1.4466x; 1.4466x over previous
//
#include <hip/hip_runtime.h>
#include <math.h>

// Word2Vec negative-sampling loss — round 2 (retry; GPU timeout last round).
// Block b (256 threads) computes losses[b]. 4 lanes per score row:
// each lane loads 8 x float4 (64B-contiguous chunks), 32 FMAs, 2-level
// shuffle reduce. Fast __expf/__logf log-sigmoid. Branchless masking.

#define O_WIN 10
#define K_NEG 10
#define DIM   128
#define ROWS  (O_WIN * (K_NEG + 1))   // 110 score rows per batch element

__global__ __launch_bounds__(256) void w2v_neg_loss_kernel(
    const float* __restrict__ center,    // [VOCAB, 128]
    const float* __restrict__ outside,   // [VOCAB, 128]
    const int*   __restrict__ cidx,      // [B]
    const int*   __restrict__ owi,       // [B, O]
    const int*   __restrict__ negs,      // [B, O, K]
    float*       __restrict__ out)       // [B]
{
    const int b   = blockIdx.x;
    const int tid = threadIdx.x;
    const int sub = tid & 3;    // lane within 4-lane row group
    const int g   = tid >> 2;   // 64 row groups per block

    __shared__ int   s_ow[O_WIN];
    __shared__ int   s_neg[O_WIN * K_NEG];
    __shared__ float s_part[4];

    if (tid < O_WIN)         s_ow[tid]  = owi[(size_t)b * O_WIN + tid];
    if (tid < O_WIN * K_NEG) s_neg[tid] = negs[(size_t)b * O_WIN * K_NEG + tid];
    __syncthreads();

    // Z fragment: lane sub owns elements {q*16 + sub*4 .. +4} for q=0..7
    // (matches the 64B-chunk W layout below). 32 VGPRs, block-uniform row
    // so it's an L1 broadcast.
    const int    c    = cidx[b];
    const float* zrow = center + (size_t)c * DIM;
    float4 zf[8];
    #pragma unroll
    for (int q = 0; q < 8; ++q)
        zf[q] = *reinterpret_cast<const float4*>(zrow + q * 16 + sub * 4);

    float acc = 0.f;

    #pragma unroll
    for (int it = 0; it < 2; ++it) {
        const int r = g + it * 64;
        if (r < ROWS) {
            const int o  = r / 11;
            const int j  = r - o * 11;        // 0 = positive, 1..10 = negative
            const int ow = s_ow[o];
            const int nx = s_neg[o * K_NEG + (j == 0 ? 0 : j - 1)];
            const int idx   = (j == 0) ? ow : nx;
            const bool valid = (ow != 0) && (idx != 0);

            const float* wrow = outside + (size_t)idx * DIM;
            float p = 0.f;
            #pragma unroll
            for (int q = 0; q < 8; ++q) {
                const float4 w = *reinterpret_cast<const float4*>(
                    wrow + q * 16 + sub * 4);
                p += w.x * zf[q].x + w.y * zf[q].y + w.z * zf[q].z + w.w * zf[q].w;
            }
            // 2-level butterfly within the 4-lane group — all 4 get the sum
            p += __shfl_xor(p, 1);
            p += __shfl_xor(p, 2);

            const float score = (j == 0) ? p : -p;
            // fast stable log-sigmoid: min(x,0) - log(1 + exp(-|x|))
            const float ls = fminf(score, 0.f)
                           - __logf(1.f + __expf(-fabsf(score)));
            acc += valid ? ls : 0.f;
        }
    }

    // Within a 4-lane group all acc are identical. Butterfly over masks
    // {4,8,16,32} sums exactly one lane from each of the wave's 16 groups.
    acc += __shfl_xor(acc, 4);
    acc += __shfl_xor(acc, 8);
    acc += __shfl_xor(acc, 16);
    acc += __shfl_xor(acc, 32);

    if ((tid & 63) == 0) s_part[tid >> 6] = acc;
    __syncthreads();

    if (tid == 0) {
        out[b] = -(s_part[0] + s_part[1] + s_part[2] + s_part[3]);
    }
}

extern "C" void kernel_launch(void* const* d_in, const int* in_sizes, int n_in,
                              void* d_out, int out_size, void* d_ws, size_t ws_size,
                              hipStream_t stream) {
    const float* center  = (const float*)d_in[0];
    const float* outside = (const float*)d_in[1];
    const int*   cw      = (const int*)d_in[2];
    const int*   ow      = (const int*)d_in[3];
    const int*   ng      = (const int*)d_in[4];
    float*       out     = (float*)d_out;

    const int B = in_sizes[2];   // 16384
    w2v_neg_loss_kernel<<<B, 256, 0, stream>>>(center, outside, cw, ow, ng, out);
}